// Round 1
// baseline (364.866 us; speedup 1.0000x reference)
//
#include <hip/hip_runtime.h>

#define TILE           4096   // positions per block
#define NTHREADS       256
#define POS_PER_THREAD 4
#define PER_ITER       (NTHREADS * POS_PER_THREAD)   // 1024 positions / block-iter
#define NITER          (TILE / PER_ITER)             // 4
#define NACC           16     // spread accumulators (cut same-address atomic contention)

// ALPHA=0.1, BETA=0.9 -> log_a == log_1b == log(0.1), log_1a == log_b == log(0.9)
#define L1C (-2.3025850929940457f)   // log(0.1)
#define L9C (-0.10536051565782628f)  // log(0.9)

// A = c1*(log c1 - log0.9) + c0*(log c0 - log0.1)   (multiplied by past1)
// B = c1*(log c1 - log0.1) + c0*(log c0 - log0.9)   (multiplied by past0; also the s=0 term)
__device__ __forceinline__ void ab(float c0, float c1, float& A, float& B) {
    const float l0 = __logf(c0), l1 = __logf(c1);
    A = c1 * (l1 - L9C) + c0 * (l0 - L1C);
    B = c1 * (l1 - L1C) + c0 * (l0 - L9C);
}

// ws layout: [0..3] u32 completion counter; [64..64+NACC*8) double accumulators.
// Host memsets first 256 bytes to 0 before launch.
__global__ __launch_bounds__(NTHREADS) void ekl_main(
    const float* __restrict__ posterior,
    const int*   __restrict__ length,
    void*        __restrict__ ws,
    float*       __restrict__ out,
    int S, int nblocks, double invB)
{
    const int b      = blockIdx.y;
    const int chunk  = blockIdx.x;
    const int cstart = chunk * TILE;
    const int tid    = threadIdx.x;
    const int len    = length[b];

    float acc = 0.0f;

    if (cstart < len || cstart == 0) {
        const float* row = posterior + (size_t)b * (size_t)S * 2u;

        if (cstart + TILE <= len) {
            // ---- full chunk: branch-free hot loop, loads burst freely ----
            #pragma unroll
            for (int j = 0; j < NITER; ++j) {
                const int s0 = cstart + j * PER_ITER + POS_PER_THREAD * tid;
                const float4 u = *(const float4*)(row + 2 * (size_t)s0);      // pos s0, s0+1
                const float4 v = *(const float4*)(row + 2 * (size_t)s0 + 4);  // pos s0+2, s0+3

                // past of s0 = position s0-1 = left lane's (v.z, v.w)
                float pvx = __shfl_up(v.z, 1, 64);
                float pvy = __shfl_up(v.w, 1, 64);
                if ((tid & 63) == 0 && s0 > 0) {            // wave boundary fixup
                    const float2 t = *(const float2*)(row + 2 * (size_t)s0 - 2);
                    pvx = t.x; pvy = t.y;
                }

                float A, B;
                ab(u.x, u.y, A, B);
                acc += (s0 == 0) ? B : (pvy * A + pvx * B); // s=0 first-term uses B only
                ab(u.z, u.w, A, B);
                acc += u.y * A + u.x * B;                   // past = (u.x,u.y)
                ab(v.x, v.y, A, B);
                acc += u.w * A + u.z * B;                   // past = (u.z,u.w)
                ab(v.z, v.w, A, B);
                acc += v.y * A + v.x * B;                   // past = (v.x,v.y)
            }
        } else {
            // ---- boundary chunk (≤1 per row): fully predicated ----
            #pragma unroll
            for (int j = 0; j < NITER; ++j) {
                const int s0 = cstart + j * PER_ITER + POS_PER_THREAD * tid;
                float4 u = make_float4(1.f, 1.f, 1.f, 1.f);
                float4 v = make_float4(1.f, 1.f, 1.f, 1.f);
                const bool a0 = (s0 < len) || (s0 == 0);
                if (a0)           u = *(const float4*)(row + 2 * (size_t)s0);
                if (s0 + 2 < len) v = *(const float4*)(row + 2 * (size_t)s0 + 4);

                // all lanes execute the shuffle (act is monotone: if this lane's
                // pv is consumed (s0<len), the left lane loaded its v).
                float pvx = __shfl_up(v.z, 1, 64);
                float pvy = __shfl_up(v.w, 1, 64);

                if (a0) {
                    if ((tid & 63) == 0 && s0 > 0) {
                        const float2 t = *(const float2*)(row + 2 * (size_t)s0 - 2);
                        pvx = t.x; pvy = t.y;
                    }
                    float A, B;
                    ab(u.x, u.y, A, B);
                    acc += (s0 == 0) ? B : (pvy * A + pvx * B);
                    if (s0 + 1 < len) {
                        ab(u.z, u.w, A, B);
                        acc += u.y * A + u.x * B;
                    }
                    if (s0 + 2 < len) {
                        ab(v.x, v.y, A, B);
                        acc += u.w * A + u.z * B;
                        if (s0 + 3 < len) {
                            ab(v.z, v.w, A, B);
                            acc += v.y * A + v.x * B;
                        }
                    }
                }
            }
        }
    }

    // 64-lane shuffle reduce, then cross-wave in double via LDS.
    #pragma unroll
    for (int off = 32; off > 0; off >>= 1)
        acc += __shfl_down(acc, off, 64);

    __shared__ double wsum[NTHREADS / 64];
    if ((tid & 63) == 0) wsum[tid >> 6] = (double)acc;
    __syncthreads();

    if (tid == 0) {
        double t = 0.0;
        #pragma unroll
        for (int i = 0; i < NTHREADS / 64; ++i) t += wsum[i];

        unsigned int* counter = (unsigned int*)ws;
        double*       accum   = (double*)((char*)ws + 64);

        if (t != 0.0)
            atomicAdd(&accum[(blockIdx.y * gridDim.x + blockIdx.x) & (NACC - 1)], t);
        __threadfence();  // make the accumulator add device-visible before counting done
        const unsigned int old = atomicAdd(counter, 1u);
        if (old == (unsigned int)(nblocks - 1)) {
            // last block: accumulators are at the coherence point (read via atomic).
            double tot = 0.0;
            #pragma unroll
            for (int i = 0; i < NACC; ++i)
                tot += atomicAdd(&accum[i], 0.0);
            out[0] = (float)(tot * invB);
        }
    }
}

extern "C" void kernel_launch(void* const* d_in, const int* in_sizes, int n_in,
                              void* d_out, int out_size, void* d_ws, size_t ws_size,
                              hipStream_t stream)
{
    const float* posterior = (const float*)d_in[0];
    const int*   length    = (const int*)d_in[1];

    const int B = in_sizes[1];                                        // 512
    const int S = (int)((long long)in_sizes[0] / ((long long)B * 2)); // 32768
    const int chunks = (S + TILE - 1) / TILE;                         // 8
    const int nblocks = chunks * B;

    // zero the counter + spread accumulators (256 B; capturable memset node)
    hipMemsetAsync(d_ws, 0, 256, stream);

    dim3 grid(chunks, B);
    ekl_main<<<grid, NTHREADS, 0, stream>>>(posterior, length, d_ws, (float*)d_out,
                                            S, nblocks, 1.0 / (double)B);
}

// Round 2
// 184.266 us; speedup vs baseline: 1.9801x; 1.9801x over previous
//
#include <hip/hip_runtime.h>

#define TILE           4096   // positions per block
#define NTHREADS       256
#define POS_PER_THREAD 4
#define PER_ITER       (NTHREADS * POS_PER_THREAD)   // 1024 positions / block-iter
#define NITER          (TILE / PER_ITER)             // 4

// ALPHA=0.1, BETA=0.9 -> log_a == log_1b == log(0.1), log_1a == log_b == log(0.9)
#define L1C (-2.3025850929940457f)   // log(0.1)
#define L9C (-0.10536051565782628f)  // log(0.9)

// A = c1*(log c1 - log0.9) + c0*(log c0 - log0.1)   (multiplied by past1)
// B = c1*(log c1 - log0.1) + c0*(log c0 - log0.9)   (multiplied by past0; also the s=0 term)
__device__ __forceinline__ void ab(float c0, float c1, float& A, float& B) {
    const float l0 = __logf(c0), l1 = __logf(c1);
    A = c1 * (l1 - L9C) + c0 * (l0 - L1C);
    B = c1 * (l1 - L1C) + c0 * (l0 - L9C);
}

// No atomics, no fences: each block writes its own partial slot (zero contention;
// round-1's fused atomic finish cost ~220us in same-cacheline cross-XCD RMWs).
__global__ __launch_bounds__(NTHREADS) void ekl_main(
    const float* __restrict__ posterior,
    const int*   __restrict__ length,
    double*      __restrict__ partial,
    int S, int chunks)
{
    const int b      = blockIdx.y;
    const int chunk  = blockIdx.x;
    const int cstart = chunk * TILE;
    const int tid    = threadIdx.x;
    const int pidx   = b * chunks + chunk;
    const int len    = length[b];

    // Whole chunk past this row's length: contributes nothing (skip its HBM reads).
    if (cstart > 0 && cstart >= len) {
        if (tid == 0) partial[pidx] = 0.0;
        return;
    }

    const float* row = posterior + (size_t)b * (size_t)S * 2u;
    float acc = 0.0f;

    if (cstart + TILE <= len) {
        // ---- full chunk (common case): branch-free hot loop, loads burst freely ----
        #pragma unroll
        for (int j = 0; j < NITER; ++j) {
            const int s0 = cstart + j * PER_ITER + POS_PER_THREAD * tid;
            const float4 u = *(const float4*)(row + 2 * (size_t)s0);      // pos s0, s0+1
            const float4 v = *(const float4*)(row + 2 * (size_t)s0 + 4);  // pos s0+2, s0+3

            // past of s0 = position s0-1 = left lane's (v.z, v.w)
            float pvx = __shfl_up(v.z, 1, 64);
            float pvy = __shfl_up(v.w, 1, 64);
            if ((tid & 63) == 0 && s0 > 0) {            // wave-boundary fixup
                const float2 t = *(const float2*)(row + 2 * (size_t)s0 - 2);
                pvx = t.x; pvy = t.y;
            }

            float A, B;
            ab(u.x, u.y, A, B);
            acc += (s0 == 0) ? B : (pvy * A + pvx * B); // s=0 first-term uses B only
            ab(u.z, u.w, A, B);
            acc += u.y * A + u.x * B;                   // past = (u.x,u.y)
            ab(v.x, v.y, A, B);
            acc += u.w * A + u.z * B;                   // past = (u.z,u.w)
            ab(v.z, v.w, A, B);
            acc += v.y * A + v.x * B;                   // past = (v.x,v.y)
        }
    } else {
        // ---- boundary chunk (≤1 per row): fully predicated ----
        #pragma unroll
        for (int j = 0; j < NITER; ++j) {
            const int s0 = cstart + j * PER_ITER + POS_PER_THREAD * tid;
            float4 u = make_float4(1.f, 1.f, 1.f, 1.f);
            float4 v = make_float4(1.f, 1.f, 1.f, 1.f);
            const bool a0 = (s0 < len) || (s0 == 0);
            if (a0)           u = *(const float4*)(row + 2 * (size_t)s0);
            if (s0 + 2 < len) v = *(const float4*)(row + 2 * (size_t)s0 + 4);

            // All lanes execute the shuffle. Activity is monotone along lanes:
            // a consumer (s0 < len) implies its left lane had s0-2 < len and
            // thus loaded v, so garbage only flows to inactive consumers.
            float pvx = __shfl_up(v.z, 1, 64);
            float pvy = __shfl_up(v.w, 1, 64);

            if (a0) {
                if ((tid & 63) == 0 && s0 > 0) {
                    const float2 t = *(const float2*)(row + 2 * (size_t)s0 - 2);
                    pvx = t.x; pvy = t.y;
                }
                float A, B;
                ab(u.x, u.y, A, B);
                acc += (s0 == 0) ? B : (pvy * A + pvx * B);
                if (s0 + 1 < len) {
                    ab(u.z, u.w, A, B);
                    acc += u.y * A + u.x * B;
                }
                if (s0 + 2 < len) {
                    ab(v.x, v.y, A, B);
                    acc += u.w * A + u.z * B;
                    if (s0 + 3 < len) {
                        ab(v.z, v.w, A, B);
                        acc += v.y * A + v.x * B;
                    }
                }
            }
        }
    }

    // 64-lane shuffle reduce, then cross-wave in double via LDS.
    #pragma unroll
    for (int off = 32; off > 0; off >>= 1)
        acc += __shfl_down(acc, off, 64);

    __shared__ double wsum[NTHREADS / 64];
    if ((tid & 63) == 0) wsum[tid >> 6] = (double)acc;
    __syncthreads();
    if (tid == 0) {
        double t = 0.0;
        #pragma unroll
        for (int i = 0; i < NTHREADS / 64; ++i) t += wsum[i];
        partial[pidx] = t;
    }
}

#define RTHREADS 1024
__global__ __launch_bounds__(RTHREADS) void ekl_reduce(
    const double* __restrict__ partial, int n,
    float* __restrict__ out, double invB)
{
    double acc = 0.0;
    for (int i = threadIdx.x; i < n; i += RTHREADS) acc += partial[i];
    #pragma unroll
    for (int off = 32; off > 0; off >>= 1)
        acc += __shfl_down(acc, off, 64);
    __shared__ double wsum[RTHREADS / 64];
    if ((threadIdx.x & 63) == 0) wsum[threadIdx.x >> 6] = acc;
    __syncthreads();
    if (threadIdx.x == 0) {
        double t = 0.0;
        #pragma unroll
        for (int i = 0; i < RTHREADS / 64; ++i) t += wsum[i];
        out[0] = (float)(t * invB);
    }
}

extern "C" void kernel_launch(void* const* d_in, const int* in_sizes, int n_in,
                              void* d_out, int out_size, void* d_ws, size_t ws_size,
                              hipStream_t stream)
{
    const float* posterior = (const float*)d_in[0];
    const int*   length    = (const int*)d_in[1];

    const int B = in_sizes[1];                                        // 512
    const int S = (int)((long long)in_sizes[0] / ((long long)B * 2)); // 32768
    const int chunks = (S + TILE - 1) / TILE;                         // 8

    double* partial = (double*)d_ws;                                  // B*chunks doubles

    dim3 grid(chunks, B);
    ekl_main<<<grid, NTHREADS, 0, stream>>>(posterior, length, partial, S, chunks);
    ekl_reduce<<<1, RTHREADS, 0, stream>>>(partial, B * chunks, (float*)d_out,
                                           1.0 / (double)B);
}